// Round 1
// baseline (888.310 us; speedup 1.0000x reference)
//
#include <hip/hip_runtime.h>
#include <math.h>

#define B_ 16
#define T_ 2048
#define H_ 512
#define K_ 15

// ---------------- zero-fill d_out (harness poisons with 0xAA) ----------------
__global__ void zero_k(float4* __restrict__ p, int n4) {
  int i = blockIdx.x * blockDim.x + threadIdx.x;
  int stride = gridDim.x * blockDim.x;
  float4 z = make_float4(0.f, 0.f, 0.f, 0.f);
  for (; i < n4; i += stride) p[i] = z;
}

// ---------------- w_eff[h] = sum_o pw2_w[o,h]*lin_w[o]; w_eff[H] = b_eff ------
__global__ void weff_k(const float* __restrict__ pw2_w, const float* __restrict__ pw2_b,
                       const float* __restrict__ lin_w, const float* __restrict__ lin_b,
                       float* __restrict__ weff) {
  __shared__ float red[512];
  int h = threadIdx.x;
  float acc = 0.f;
  for (int o = 0; o < H_; ++o) acc += pw2_w[o * H_ + h] * lin_w[o];
  weff[h] = acc;
  red[h] = pw2_b[h] * lin_w[h];
  __syncthreads();
  for (int s = 256; s > 0; s >>= 1) {
    if (h < s) red[h] += red[h + s];
    __syncthreads();
  }
  if (h == 0) weff[H_] = red[0] + lin_b[0];
}

// ---------------- pw1 GEMM (fp32) + GLU -------------------------------------
// C[m,n] = sum_k X[m,k] * W[n,k]; g[m,j] = (C[m,j]+b[j]) * sigmoid(C[m,j+512]+b[j+512])
// Block: 128 rows x 64 g-cols (=128 C-cols: 64 'a' + 64 'gate'). 256 thr, 8x8 microtile.
__global__ __launch_bounds__(256) void gemm_glu_k(const float* __restrict__ X,
    const float* __restrict__ W, const float* __restrict__ bias, float* __restrict__ g) {
  __shared__ float Xs[16][128];  // [k][m_local]
  __shared__ float Ws[16][128];  // [k][n_local] (0..63 = a-cols, 64..127 = gate-cols)
  const int tid = threadIdx.x;
  const int m0 = blockIdx.x * 128;
  const int nbase = blockIdx.y * 64;
  const int tm4 = (tid >> 4) << 2;
  const int tn4 = (tid & 15) << 2;
  const int r = tid >> 2;          // 0..63
  const int c4 = (tid & 3) << 2;   // 0,4,8,12

  const float* Xp0 = X + (size_t)(m0 + r) * 512 + c4;
  const float* Xp1 = Xp0 + (size_t)64 * 512;
  const float* Wp0 = W + (size_t)(nbase + r) * 512 + c4;
  const float* Wp1 = W + (size_t)(nbase + 512 + r) * 512 + c4;

  float acc[8][8];
#pragma unroll
  for (int i = 0; i < 8; ++i)
#pragma unroll
    for (int j = 0; j < 8; ++j) acc[i][j] = 0.f;

  float4 xv0 = *(const float4*)(Xp0);
  float4 xv1 = *(const float4*)(Xp1);
  float4 wv0 = *(const float4*)(Wp0);
  float4 wv1 = *(const float4*)(Wp1);

  for (int kk = 0; kk < 32; ++kk) {
    __syncthreads();
    Xs[c4 + 0][r] = xv0.x; Xs[c4 + 1][r] = xv0.y; Xs[c4 + 2][r] = xv0.z; Xs[c4 + 3][r] = xv0.w;
    Xs[c4 + 0][64 + r] = xv1.x; Xs[c4 + 1][64 + r] = xv1.y; Xs[c4 + 2][64 + r] = xv1.z; Xs[c4 + 3][64 + r] = xv1.w;
    Ws[c4 + 0][r] = wv0.x; Ws[c4 + 1][r] = wv0.y; Ws[c4 + 2][r] = wv0.z; Ws[c4 + 3][r] = wv0.w;
    Ws[c4 + 0][64 + r] = wv1.x; Ws[c4 + 1][64 + r] = wv1.y; Ws[c4 + 2][64 + r] = wv1.z; Ws[c4 + 3][64 + r] = wv1.w;
    __syncthreads();
    if (kk < 31) {  // prefetch next tile while computing
      int k0 = (kk + 1) * 16;
      xv0 = *(const float4*)(Xp0 + k0);
      xv1 = *(const float4*)(Xp1 + k0);
      wv0 = *(const float4*)(Wp0 + k0);
      wv1 = *(const float4*)(Wp1 + k0);
    }
#pragma unroll
    for (int k = 0; k < 16; ++k) {
      float4 a0 = *(const float4*)(&Xs[k][tm4]);
      float4 a1 = *(const float4*)(&Xs[k][tm4 + 64]);
      float4 b0 = *(const float4*)(&Ws[k][tn4]);
      float4 b1 = *(const float4*)(&Ws[k][tn4 + 64]);
      float av[8] = {a0.x, a0.y, a0.z, a0.w, a1.x, a1.y, a1.z, a1.w};
      float bv[8] = {b0.x, b0.y, b0.z, b0.w, b1.x, b1.y, b1.z, b1.w};
#pragma unroll
      for (int i = 0; i < 8; ++i)
#pragma unroll
        for (int j = 0; j < 8; ++j) acc[i][j] += av[i] * bv[j];
    }
  }

#pragma unroll
  for (int rh = 0; rh < 2; ++rh) {
#pragma unroll
    for (int i = 0; i < 4; ++i) {
      int m = m0 + rh * 64 + tm4 + i;
      float4 outv;
      float* ov = (float*)&outv;
#pragma unroll
      for (int cth = 0; cth < 4; ++cth) {
        float aval = acc[rh * 4 + i][cth] + bias[nbase + tn4 + cth];
        float gate = acc[rh * 4 + i][cth + 4] + bias[512 + nbase + tn4 + cth];
        ov[cth] = aval / (1.f + expf(-gate));
      }
      *(float4*)(g + (size_t)m * 512 + nbase + tn4) = outv;
    }
  }
}

// ---------------- depthwise conv + LN + swish + logit-dot + sigmoid ----------
// Block: (t-tile of 16, b). 512 threads, thread = channel c. Writes alphas[b,t].
__global__ __launch_bounds__(512) void conv_ln_k(const float* __restrict__ g,
    const float* __restrict__ dw_w, const float* __restrict__ dw_b,
    const float* __restrict__ ln_g, const float* __restrict__ ln_b,
    const float* __restrict__ weff, const int* __restrict__ x_lens,
    float* __restrict__ alphas) {
  __shared__ float wlds[H_ * K_];
  __shared__ float red1[16][8];
  __shared__ float red2[16][8];
  __shared__ float mvs[16], rss[16];
  const int tid = threadIdx.x;
  const int c = tid;
  const int t0 = blockIdx.x * 16;
  const int b = blockIdx.y;

  for (int i = tid; i < H_ * K_; i += 512) wlds[i] = dw_w[i];
  __syncthreads();

  const float* gb = g + ((size_t)b * T_) * H_ + c;
  float gv[30];
#pragma unroll
  for (int i = 0; i < 30; ++i) {
    int t = t0 - 14 + i;
    gv[i] = (t >= 0) ? gb[(size_t)t * H_] : 0.f;
  }
  float wreg[15];
#pragma unroll
  for (int k = 0; k < 15; ++k) wreg[k] = wlds[c * 15 + k];
  float dwb = dw_b[c];
  float h2[16];
#pragma unroll
  for (int j = 0; j < 16; ++j) {
    float s = dwb;
#pragma unroll
    for (int k = 0; k < 15; ++k) s += gv[j + k] * wreg[k];
    h2[j] = s;
  }
  const int lane = tid & 63, wid = tid >> 6;
#pragma unroll
  for (int j = 0; j < 16; ++j) {
    float s1 = h2[j], s2 = h2[j] * h2[j];
#pragma unroll
    for (int off = 32; off > 0; off >>= 1) {
      s1 += __shfl_down(s1, off, 64);
      s2 += __shfl_down(s2, off, 64);
    }
    if (lane == 0) { red1[j][wid] = s1; red2[j][wid] = s2; }
  }
  __syncthreads();
  if (tid < 16) {
    float s1 = 0.f, s2 = 0.f;
#pragma unroll
    for (int w = 0; w < 8; ++w) { s1 += red1[tid][w]; s2 += red2[tid][w]; }
    float m = s1 * (1.f / 512.f);
    float v = s2 * (1.f / 512.f) - m * m;
    mvs[tid] = m;
    rss[tid] = rsqrtf(v + 1e-5f);
  }
  __syncthreads();
  float lg = ln_g[c], lb = ln_b[c], we = weff[c];
#pragma unroll
  for (int j = 0; j < 16; ++j) {
    float y = (h2[j] - mvs[j]) * rss[j] * lg + lb;
    float sw = y / (1.f + expf(-y));
    float p = sw * we;
#pragma unroll
    for (int off = 32; off > 0; off >>= 1) p += __shfl_down(p, off, 64);
    if (lane == 0) red1[j][wid] = p;
  }
  __syncthreads();
  if (tid < 16) {
    float s = 0.f;
#pragma unroll
    for (int w = 0; w < 8; ++w) s += red1[tid][w];
    float logit = s + weff[H_];
    float a = 1.f / (1.f + expf(-logit));
    int t = t0 + tid;
    if (t >= x_lens[b]) a = 0.f;
    alphas[b * T_ + t] = a;
  }
}

// ---------------- CIF sequential scan (exact reference fp32 op order) --------
__global__ void cif_scan_k(const float* __restrict__ alphas, float* __restrict__ wd,
    float* __restrict__ wr, int* __restrict__ fire_pos, int* __restrict__ nfires,
    float* __restrict__ tok) {
  int b = threadIdx.x;
  if (b >= B_) return;
  const float* ar = alphas + b * T_;
  float* wdr = wd + b * T_;
  float* wrr = wr + b * T_;
  int* fp = fire_pos + b * T_;
  float integ = 0.f, tsum = 0.f;
  int cnt = 0;
  for (int t = 0; t < T_; t += 4) {
    float4 av = *(const float4*)(ar + t);
    float a[4] = {av.x, av.y, av.z, av.w};
    float cur4[4], rem4[4];
#pragma unroll
    for (int i = 0; i < 4; ++i) {
      float al = a[i];
      float dist = 1.0f - integ;    // uses OLD integ, as reference
      float ni = integ + al;        // single fp32 add, as reference
      bool fire = ni >= 1.0f;
      float cur = fire ? dist : al;
      float rem = al - cur;
      cur4[i] = cur;
      rem4[i] = rem;
      if (fire) { fp[cnt++] = t + i; ni -= 1.0f; }  // exact for ni in [1,2)
      integ = ni;
      tsum += al;
    }
    *(float4*)(wdr + t) = make_float4(cur4[0], cur4[1], cur4[2], cur4[3]);
    *(float4*)(wrr + t) = make_float4(rem4[0], rem4[1], rem4[2], rem4[3]);
  }
  nfires[b] = cnt;
  tok[b] = tsum;
}

// ---------------- gather fired frames + reversed copy ------------------------
// frame_j = wr[t_{j-1}]*x[t_{j-1}] + sum_{t in (t_{j-1},t_j)} alpha_t*x[t] + wd[t_j]*x[t_j]
__global__ __launch_bounds__(128) void frames_k(const float* __restrict__ x,
    const float* __restrict__ alphas, const float* __restrict__ wd,
    const float* __restrict__ wr, const int* __restrict__ fire_pos,
    const int* __restrict__ nfires, float* __restrict__ out0, float* __restrict__ out2) {
  const int b = blockIdx.y;
  const int j = blockIdx.x;
  if (j >= nfires[b]) return;
  const int te = fire_pos[b * T_ + j];
  const int ts = (j > 0) ? fire_pos[b * T_ + j - 1] : -1;
  const int h = threadIdx.x << 2;
  const float* xb = x + ((size_t)b * T_) * H_;
  float4 acc = make_float4(0.f, 0.f, 0.f, 0.f);
  if (j > 0) {
    float w = wr[b * T_ + ts];
    float4 xv = *(const float4*)(xb + (size_t)ts * H_ + h);
    acc.x = w * xv.x; acc.y = w * xv.y; acc.z = w * xv.z; acc.w = w * xv.w;
  }
  for (int t = ts + 1; t < te; ++t) {
    float w = alphas[b * T_ + t];
    float4 xv = *(const float4*)(xb + (size_t)t * H_ + h);
    acc.x += w * xv.x; acc.y += w * xv.y; acc.z += w * xv.z; acc.w += w * xv.w;
  }
  {
    float w = wd[b * T_ + te];
    float4 xv = *(const float4*)(xb + (size_t)te * H_ + h);
    acc.x += w * xv.x; acc.y += w * xv.y; acc.z += w * xv.z; acc.w += w * xv.w;
  }
  size_t ob = ((size_t)b * T_ + j) * H_;
  *(float4*)(out0 + ob + h) = acc;
  float4 racc = make_float4(acc.w, acc.z, acc.y, acc.x);
  *(float4*)(out2 + ob + (H_ - 4 - h)) = racc;  // flip along H
}

extern "C" void kernel_launch(void* const* d_in, const int* in_sizes, int n_in,
                              void* d_out, int out_size, void* d_ws, size_t ws_size,
                              hipStream_t stream) {
  const float* x     = (const float*)d_in[0];
  const int*   xlens = (const int*)d_in[1];
  const float* pw1_w = (const float*)d_in[2];
  const float* pw1_b = (const float*)d_in[3];
  const float* dw_w  = (const float*)d_in[4];
  const float* dw_b  = (const float*)d_in[5];
  const float* ln_g  = (const float*)d_in[6];
  const float* ln_b  = (const float*)d_in[7];
  const float* pw2_w = (const float*)d_in[8];
  const float* pw2_b = (const float*)d_in[9];
  const float* lin_w = (const float*)d_in[10];
  const float* lin_b = (const float*)d_in[11];

  float* out0 = (float*)d_out;                       // fired_frames (B,T,H)
  float* tok  = out0 + (size_t)B_ * T_ * H_;         // predicted_token_nums (B,)
  float* out2 = tok + B_;                            // r_fired_frames (B,T,H)

  char* ws = (char*)d_ws;
  float* g        = (float*)ws;                                   // 64 MB
  float* alphas   = (float*)(ws + (size_t)B_ * T_ * H_ * 4);
  float* wd       = alphas + B_ * T_;
  float* wr       = wd + B_ * T_;
  int*   fire_pos = (int*)(wr + B_ * T_);
  int*   nfires   = fire_pos + B_ * T_;
  float* weff     = (float*)(nfires + 64);

  int n4 = out_size / 4;
  zero_k<<<2048, 256, 0, stream>>>((float4*)d_out, n4);
  weff_k<<<1, 512, 0, stream>>>(pw2_w, pw2_b, lin_w, lin_b, weff);
  gemm_glu_k<<<dim3(256, 8), 256, 0, stream>>>(x, pw1_w, pw1_b, g);
  conv_ln_k<<<dim3(128, 16), 512, 0, stream>>>(g, dw_w, dw_b, ln_g, ln_b, weff, xlens, alphas);
  cif_scan_k<<<1, 64, 0, stream>>>(alphas, wd, wr, fire_pos, nfires, tok);
  frames_k<<<dim3(2048, 16), 128, 0, stream>>>(x, alphas, wd, wr, fire_pos, nfires, out0, out2);
}

// Round 2
// 651.793 us; speedup vs baseline: 1.3629x; 1.3629x over previous
//
#include <hip/hip_runtime.h>
#include <math.h>

#define B_ 16
#define T_ 2048
#define H_ 512
#define K_ 15
#define M_ (B_*T_)   // 32768

typedef __attribute__((ext_vector_type(8))) short short8;
typedef __attribute__((ext_vector_type(4))) float f32x4;

__device__ __forceinline__ unsigned short f2bf(float f) {
  union { float f; unsigned u; } v; v.f = f;
  unsigned r = v.u + 0x7FFFu + ((v.u >> 16) & 1u);
  return (unsigned short)(r >> 16);
}
__device__ __forceinline__ float bf2f(unsigned short b) {
  union { float f; unsigned u; } v; v.u = ((unsigned)b) << 16;
  return v.f;
}

__device__ __forceinline__ void async_load16(const void* g, void* l) {
  __builtin_amdgcn_global_load_lds((const __attribute__((address_space(1))) void*)g,
                                   (__attribute__((address_space(3))) void*)l, 16, 0, 0);
}

// ---------------- fp32 -> (bf16 hi, bf16 lo) split conversion ----------------
__global__ void convx_k(const float* __restrict__ x, unsigned short* __restrict__ hi,
                        unsigned short* __restrict__ lo, int n4) {
  int i = blockIdx.x * blockDim.x + threadIdx.x;
  int stride = gridDim.x * blockDim.x;
  for (; i < n4; i += stride) {
    float4 v = ((const float4*)x)[i];
    ushort4 h, l;
    h.x = f2bf(v.x); l.x = f2bf(v.x - bf2f(h.x));
    h.y = f2bf(v.y); l.y = f2bf(v.y - bf2f(h.y));
    h.z = f2bf(v.z); l.z = f2bf(v.z - bf2f(h.z));
    h.w = f2bf(v.w); l.w = f2bf(v.w - bf2f(h.w));
    ((ushort4*)hi)[i] = h;
    ((ushort4*)lo)[i] = l;
  }
}

// ---------------- w_eff[h] = sum_o pw2_w[o,h]*lin_w[o] ----------------------
__global__ __launch_bounds__(256) void weff_k(const float* __restrict__ pw2_w,
    const float* __restrict__ lin_w, float* __restrict__ weff) {
  __shared__ float red[256];
  int h = blockIdx.x * 64 + (threadIdx.x & 63);
  int og = threadIdx.x >> 6;
  float acc = 0.f;
  for (int o = og * 128; o < og * 128 + 128; ++o) acc += pw2_w[o * H_ + h] * lin_w[o];
  red[threadIdx.x] = acc;
  __syncthreads();
  if (threadIdx.x < 64)
    weff[h] = red[threadIdx.x] + red[threadIdx.x + 64] + red[threadIdx.x + 128] + red[threadIdx.x + 192];
}

__global__ void beff_k(const float* __restrict__ pw2_b, const float* __restrict__ lin_w,
                       const float* __restrict__ lin_b, float* __restrict__ weff) {
  __shared__ float red[512];
  int h = threadIdx.x;
  red[h] = pw2_b[h] * lin_w[h];
  __syncthreads();
  for (int s = 256; s > 0; s >>= 1) {
    if (h < s) red[h] += red[h + s];
    __syncthreads();
  }
  if (h == 0) weff[H_] = red[0] + lin_b[0];
}

// ---------------- pw1 GEMM via bf16 hi/lo-split MFMA + GLU epilogue ----------
// C[m,n] = sum_k X[m,k]*W[n,k] over 3 phases: Xhi*Whi + Xlo*Whi + Xhi*Wlo.
// Block: 128 rows x 64 g-cols (B-tile rows 0..63 = a-cols n0..n0+63, rows
// 64..127 = gate-cols n0+512..). 4 waves, wave = 32 rows x 128 cols.
// LDS tiles 128x64 bf16, XOR-swizzled 16B chunks to stay conflict-free for
// both global_load_lds staging (lane-contiguous) and ds_read_b128 fragments.
__global__ __launch_bounds__(256) void gemm_mfma_k(
    const unsigned short* __restrict__ Ahi, const unsigned short* __restrict__ Alo,
    const unsigned short* __restrict__ Whi, const unsigned short* __restrict__ Wlo,
    const float* __restrict__ bias, float* __restrict__ g) {
  __shared__ short As[128 * 64];
  __shared__ short Bs[128 * 64];
  const int tid = threadIdx.x;
  const int m0 = blockIdx.x * 128;
  const int n0 = blockIdx.y * 64;
  const int w = tid >> 6;
  const int lane = tid & 63;

  f32x4 acc[2][8];
#pragma unroll
  for (int mt = 0; mt < 2; ++mt)
#pragma unroll
    for (int nt = 0; nt < 8; ++nt) acc[mt][nt] = (f32x4){0.f, 0.f, 0.f, 0.f};

  const unsigned short* Aptr[3] = {Ahi, Alo, Ahi};
  const unsigned short* Bptr[3] = {Whi, Whi, Wlo};

  // per-lane staging geometry (constant across tiles)
  const int srow[4] = {(0 * 256 + tid) >> 3, (1 * 256 + tid) >> 3,
                       (2 * 256 + tid) >> 3, (3 * 256 + tid) >> 3};
  const int scc = tid & 7;

  for (int p = 0; p < 3; ++p) {
    const unsigned short* Ab = Aptr[p];
    const unsigned short* Bb = Bptr[p];
#pragma unroll 1
    for (int kk = 0; kk < 8; ++kk) {
      const int k0 = kk * 64;
      __syncthreads();
#pragma unroll
      for (int j = 0; j < 4; ++j) {
        int row = srow[j];
        int csrc = scc ^ (row & 7);
        int lbase = __builtin_amdgcn_readfirstlane((j * 256 + w * 64) * 8);
        async_load16(Ab + (size_t)(m0 + row) * 512 + k0 + csrc * 8, &As[lbase]);
        int wrow = (row < 64) ? (n0 + row) : (n0 + 448 + row);
        async_load16(Bb + (size_t)wrow * 512 + k0 + csrc * 8, &Bs[lbase]);
      }
      __syncthreads();
#pragma unroll
      for (int ks = 0; ks < 2; ++ks) {
        const int swz = (ks * 4 + (lane >> 4)) ^ (lane & 7);
        const int rA = w * 32 + (lane & 15);
        const int rB = lane & 15;
        short8 af[2], bfr[8];
#pragma unroll
        for (int mt = 0; mt < 2; ++mt)
          af[mt] = *(const short8*)&As[((rA + mt * 16) * 8 + swz) * 8];
#pragma unroll
        for (int nt = 0; nt < 8; ++nt)
          bfr[nt] = *(const short8*)&Bs[((rB + nt * 16) * 8 + swz) * 8];
#pragma unroll
        for (int mt = 0; mt < 2; ++mt)
#pragma unroll
          for (int nt = 0; nt < 8; ++nt)
            acc[mt][nt] = __builtin_amdgcn_mfma_f32_16x16x32_bf16(af[mt], bfr[nt], acc[mt][nt], 0, 0, 0);
      }
    }
  }

  // epilogue: GLU. a-cols = acc[.][0..3], gate-cols = acc[.][4..7]
  const int col = lane & 15, rq = lane >> 4;
#pragma unroll
  for (int mt = 0; mt < 2; ++mt) {
#pragma unroll
    for (int nt = 0; nt < 4; ++nt) {
      int gcol = n0 + nt * 16 + col;
      float ba = bias[gcol];
      float bg = bias[512 + gcol];
#pragma unroll
      for (int r = 0; r < 4; ++r) {
        int grow = m0 + w * 32 + mt * 16 + rq * 4 + r;
        float a = acc[mt][nt][r] + ba;
        float gt = acc[mt][nt + 4][r] + bg;
        g[(size_t)grow * 512 + gcol] = a / (1.f + expf(-gt));
      }
    }
  }
}

// ---------------- depthwise conv + LN + swish + logit-dot + sigmoid ----------
__global__ __launch_bounds__(512) void conv_ln_k(const float* __restrict__ g,
    const float* __restrict__ dw_w, const float* __restrict__ dw_b,
    const float* __restrict__ ln_g, const float* __restrict__ ln_b,
    const float* __restrict__ weff, const int* __restrict__ x_lens,
    float* __restrict__ alphas) {
  __shared__ float wlds[H_ * K_];
  __shared__ float red1[16][8];
  __shared__ float red2[16][8];
  __shared__ float mvs[16], rss[16];
  const int tid = threadIdx.x;
  const int c = tid;
  const int t0 = blockIdx.x * 16;
  const int b = blockIdx.y;

  for (int i = tid; i < H_ * K_; i += 512) wlds[i] = dw_w[i];
  __syncthreads();

  const float* gb = g + ((size_t)b * T_) * H_ + c;
  float gv[30];
#pragma unroll
  for (int i = 0; i < 30; ++i) {
    int t = t0 - 14 + i;
    gv[i] = (t >= 0) ? gb[(size_t)t * H_] : 0.f;
  }
  float wreg[15];
#pragma unroll
  for (int k = 0; k < 15; ++k) wreg[k] = wlds[c * 15 + k];
  float dwb = dw_b[c];
  float h2[16];
#pragma unroll
  for (int j = 0; j < 16; ++j) {
    float s = dwb;
#pragma unroll
    for (int k = 0; k < 15; ++k) s += gv[j + k] * wreg[k];
    h2[j] = s;
  }
  const int lane = tid & 63, wid = tid >> 6;
#pragma unroll
  for (int j = 0; j < 16; ++j) {
    float s1 = h2[j], s2 = h2[j] * h2[j];
#pragma unroll
    for (int off = 32; off > 0; off >>= 1) {
      s1 += __shfl_down(s1, off, 64);
      s2 += __shfl_down(s2, off, 64);
    }
    if (lane == 0) { red1[j][wid] = s1; red2[j][wid] = s2; }
  }
  __syncthreads();
  if (tid < 16) {
    float s1 = 0.f, s2 = 0.f;
#pragma unroll
    for (int w = 0; w < 8; ++w) { s1 += red1[tid][w]; s2 += red2[tid][w]; }
    float m = s1 * (1.f / 512.f);
    float v = s2 * (1.f / 512.f) - m * m;
    mvs[tid] = m;
    rss[tid] = rsqrtf(v + 1e-5f);
  }
  __syncthreads();
  float lg = ln_g[c], lb = ln_b[c], we = weff[c];
#pragma unroll
  for (int j = 0; j < 16; ++j) {
    float y = (h2[j] - mvs[j]) * rss[j] * lg + lb;
    float sw = y / (1.f + expf(-y));
    float p = sw * we;
#pragma unroll
    for (int off = 32; off > 0; off >>= 1) p += __shfl_down(p, off, 64);
    if (lane == 0) red1[j][wid] = p;
  }
  __syncthreads();
  if (tid < 16) {
    float s = 0.f;
#pragma unroll
    for (int w = 0; w < 8; ++w) s += red1[tid][w];
    float logit = s + weff[H_];
    float a = 1.f / (1.f + expf(-logit));
    int t = t0 + tid;
    if (t >= x_lens[b]) a = 0.f;
    alphas[b * T_ + t] = a;
  }
}

// ---------------- CIF sequential scan (exact reference fp32 op order) --------
__global__ void cif_scan_k(const float* __restrict__ alphas, float* __restrict__ wd,
    float* __restrict__ wr, int* __restrict__ fire_pos, int* __restrict__ nfires,
    float* __restrict__ tok) {
  int b = threadIdx.x;
  if (b >= B_) return;
  const float* ar = alphas + b * T_;
  float* wdr = wd + b * T_;
  float* wrr = wr + b * T_;
  int* fp = fire_pos + b * T_;
  float integ = 0.f, tsum = 0.f;
  int cnt = 0;
  for (int t = 0; t < T_; t += 4) {
    float4 av = *(const float4*)(ar + t);
    float a[4] = {av.x, av.y, av.z, av.w};
    float cur4[4], rem4[4];
#pragma unroll
    for (int i = 0; i < 4; ++i) {
      float al = a[i];
      float dist = 1.0f - integ;
      float ni = integ + al;
      bool fire = ni >= 1.0f;
      float cur = fire ? dist : al;
      float rem = al - cur;
      cur4[i] = cur;
      rem4[i] = rem;
      if (fire) { fp[cnt++] = t + i; ni -= 1.0f; }
      integ = ni;
      tsum += al;
    }
    *(float4*)(wdr + t) = make_float4(cur4[0], cur4[1], cur4[2], cur4[3]);
    *(float4*)(wrr + t) = make_float4(rem4[0], rem4[1], rem4[2], rem4[3]);
  }
  nfires[b] = cnt;
  tok[b] = tsum;
}

// ---------------- gather fired frames + reversed copy + zero-fill tail -------
__global__ __launch_bounds__(128) void frames_k(const float* __restrict__ x,
    const float* __restrict__ alphas, const float* __restrict__ wd,
    const float* __restrict__ wr, const int* __restrict__ fire_pos,
    const int* __restrict__ nfires, float* __restrict__ out0, float* __restrict__ out2) {
  const int b = blockIdx.y;
  const int j = blockIdx.x;
  const int h = threadIdx.x << 2;
  const size_t ob = ((size_t)b * T_ + j) * H_;
  if (j >= nfires[b]) {   // d_out is poisoned 0xAA: zero the unused rows here
    float4 z = make_float4(0.f, 0.f, 0.f, 0.f);
    *(float4*)(out0 + ob + h) = z;
    *(float4*)(out2 + ob + h) = z;
    return;
  }
  const int te = fire_pos[b * T_ + j];
  const int ts = (j > 0) ? fire_pos[b * T_ + j - 1] : -1;
  const float* xb = x + ((size_t)b * T_) * H_;
  float4 acc = make_float4(0.f, 0.f, 0.f, 0.f);
  if (j > 0) {
    float w = wr[b * T_ + ts];
    float4 xv = *(const float4*)(xb + (size_t)ts * H_ + h);
    acc.x = w * xv.x; acc.y = w * xv.y; acc.z = w * xv.z; acc.w = w * xv.w;
  }
  for (int t = ts + 1; t < te; ++t) {
    float w = alphas[b * T_ + t];
    float4 xv = *(const float4*)(xb + (size_t)t * H_ + h);
    acc.x += w * xv.x; acc.y += w * xv.y; acc.z += w * xv.z; acc.w += w * xv.w;
  }
  {
    float w = wd[b * T_ + te];
    float4 xv = *(const float4*)(xb + (size_t)te * H_ + h);
    acc.x += w * xv.x; acc.y += w * xv.y; acc.z += w * xv.z; acc.w += w * xv.w;
  }
  *(float4*)(out0 + ob + h) = acc;
  float4 racc = make_float4(acc.w, acc.z, acc.y, acc.x);
  *(float4*)(out2 + ob + (H_ - 4 - h)) = racc;
}

extern "C" void kernel_launch(void* const* d_in, const int* in_sizes, int n_in,
                              void* d_out, int out_size, void* d_ws, size_t ws_size,
                              hipStream_t stream) {
  const float* x     = (const float*)d_in[0];
  const int*   xlens = (const int*)d_in[1];
  const float* pw1_w = (const float*)d_in[2];
  const float* pw1_b = (const float*)d_in[3];
  const float* dw_w  = (const float*)d_in[4];
  const float* dw_b  = (const float*)d_in[5];
  const float* ln_g  = (const float*)d_in[6];
  const float* ln_b  = (const float*)d_in[7];
  const float* pw2_w = (const float*)d_in[8];
  const float* pw2_b = (const float*)d_in[9];
  const float* lin_w = (const float*)d_in[10];
  const float* lin_b = (const float*)d_in[11];

  float* out0 = (float*)d_out;                       // fired_frames (B,T,H)
  float* tok  = out0 + (size_t)B_ * T_ * H_;         // predicted_token_nums (B,)
  float* out2 = tok + B_;                            // r_fired_frames (B,T,H)

  char* ws = (char*)d_ws;
  float* g             = (float*)ws;                              // 64 MB
  unsigned short* Ahi  = (unsigned short*)(ws + (size_t)M_ * H_ * 4);
  unsigned short* Alo  = Ahi + (size_t)M_ * H_;
  unsigned short* Whi  = Alo + (size_t)M_ * H_;
  unsigned short* Wlo  = Whi + (size_t)2 * H_ * H_;
  float* alphas   = (float*)(Wlo + (size_t)2 * H_ * H_);
  float* wd       = alphas + B_ * T_;
  float* wr       = wd + B_ * T_;
  int*   fire_pos = (int*)(wr + B_ * T_);
  int*   nfires   = fire_pos + B_ * T_;
  float* weff     = (float*)(nfires + 64);

  convx_k<<<2048, 256, 0, stream>>>(x, Ahi, Alo, M_ * H_ / 4);
  convx_k<<<256, 256, 0, stream>>>(pw1_w, Whi, Wlo, 2 * H_ * H_ / 4);
  weff_k<<<8, 256, 0, stream>>>(pw2_w, lin_w, weff);
  beff_k<<<1, 512, 0, stream>>>(pw2_b, lin_w, lin_b, weff);
  gemm_mfma_k<<<dim3(256, 8), 256, 0, stream>>>(Ahi, Alo, Whi, Wlo, pw1_b, g);
  conv_ln_k<<<dim3(128, 16), 512, 0, stream>>>(g, dw_w, dw_b, ln_g, ln_b, weff, xlens, alphas);
  cif_scan_k<<<1, 64, 0, stream>>>(alphas, wd, wr, fire_pos, nfires, tok);
  frames_k<<<dim3(2048, 16), 128, 0, stream>>>(x, alphas, wd, wr, fire_pos, nfires, out0, out2);
}